// Round 1
// baseline (441.017 us; speedup 1.0000x reference)
//
#include <hip/hip_runtime.h>

// Blur2: upfirdn2d(up=1, down=1, pad=(2,1)) with a separable 4x4 kernel,
// depthwise over (N=8, C=128, H=256, W=256) fp32.
//
// out[i,j] = sum_{a,b in 0..3} x[i+a-2, j+b-2] * K[3-a][3-b]   (zero-padded)
// K is rank-1 (outer product): K[p][q] = tr[p]*tc[q]. We factor it at runtime
// from the kernel input (tr[1]=tc[1]=sqrt(K[1][1]) for this symmetric blur),
// then do horizontal conv h(r,j) = sum_v tc[3-v'] x[r, j+v'-2] followed by a
// vertical conv over a rolling 4-row register window.

#define LANES 64
#define TY 4
#define ROWS_PER_TY 16
#define TILE_H (TY * ROWS_PER_TY) // 64 output rows per block

__global__ __launch_bounds__(256, 4) void blur2_kernel(
    const float* __restrict__ x, const float* __restrict__ kern,
    float* __restrict__ out, int H, int W, int tilesH)
{
    const int lane = threadIdx.x;            // 0..63, one wave per ty row
    const int ty   = threadIdx.y;            // 0..3
    const int tile  = blockIdx.x % tilesH;
    const int plane = blockIdx.x / tilesH;

    // ---- separable factorization of the flipped 4x4 kernel ----
    // column weights applied to {x[j-2], x[j-1], x[j], x[j+1]}: tc[3],tc[2],tc[1],tc[0]
    // row    weights applied to rows {i-2, i-1, i, i+1}:        tr[3],tr[2],tr[1],tr[0]
    const float s     = sqrtf(kern[1 * 4 + 1]);   // tr[1] = tc[1] (symmetric blur)
    const float inv_s = 1.0f / s;
    const float cw0 = kern[1 * 4 + 3] * inv_s;    // tc[3]
    const float cw1 = kern[1 * 4 + 2] * inv_s;    // tc[2]
    const float cw2 = kern[1 * 4 + 1] * inv_s;    // tc[1]
    const float cw3 = kern[1 * 4 + 0] * inv_s;    // tc[0]
    const float rw0 = kern[3 * 4 + 1] * inv_s;    // tr[3]
    const float rw1 = kern[2 * 4 + 1] * inv_s;    // tr[2]
    const float rw2 = kern[1 * 4 + 1] * inv_s;    // tr[1]
    const float rw3 = kern[0 * 4 + 1] * inv_s;    // tr[0]

    const size_t plane_off = (size_t)plane * H * W;
    const float* xp = x + plane_off;
    float*       op = out + plane_off;

    const int j0 = lane * 4;                      // 4 output columns per thread
    const int i0 = tile * TILE_H + ty * ROWS_PER_TY;

    // load input row r, return horizontal conv for this thread's 4 columns
    auto loadh = [&](int r) -> float4 {
        float4 a = make_float4(0.f, 0.f, 0.f, 0.f);
        if ((unsigned)r < (unsigned)H)
            a = *reinterpret_cast<const float4*>(xp + (size_t)r * W + j0);
        // halo columns from neighbor lanes (W edges are zero pad)
        float xm2 = __shfl_up(a.z, 1, LANES);     // x[j0-2]
        float xm1 = __shfl_up(a.w, 1, LANES);     // x[j0-1]
        float xq4 = __shfl_down(a.x, 1, LANES);   // x[j0+4]
        if (lane == 0)         { xm2 = 0.f; xm1 = 0.f; }
        if (lane == LANES - 1) { xq4 = 0.f; }
        float4 h;
        h.x = cw0 * xm2 + cw1 * xm1 + cw2 * a.x + cw3 * a.y;
        h.y = cw0 * xm1 + cw1 * a.x + cw2 * a.y + cw3 * a.z;
        h.z = cw0 * a.x + cw1 * a.y + cw2 * a.z + cw3 * a.w;
        h.w = cw0 * a.y + cw1 * a.z + cw2 * a.w + cw3 * xq4;
        return h;
    };

    float4 h0 = loadh(i0 - 2);
    float4 h1 = loadh(i0 - 1);
    float4 h2 = loadh(i0);
#pragma unroll
    for (int rr = 0; rr < ROWS_PER_TY; ++rr) {
        const int i = i0 + rr;
        float4 h3 = loadh(i + 1);
        float4 o;
        o.x = rw0 * h0.x + rw1 * h1.x + rw2 * h2.x + rw3 * h3.x;
        o.y = rw0 * h0.y + rw1 * h1.y + rw2 * h2.y + rw3 * h3.y;
        o.z = rw0 * h0.z + rw1 * h1.z + rw2 * h2.z + rw3 * h3.z;
        o.w = rw0 * h0.w + rw1 * h1.w + rw2 * h2.w + rw3 * h3.w;
        *reinterpret_cast<float4*>(op + (size_t)i * W + j0) = o;
        h0 = h1; h1 = h2; h2 = h3;
    }
}

extern "C" void kernel_launch(void* const* d_in, const int* in_sizes, int n_in,
                              void* d_out, int out_size, void* d_ws, size_t ws_size,
                              hipStream_t stream) {
    const float* x    = (const float*)d_in[0];
    const float* kern = (const float*)d_in[1];
    float*       out  = (float*)d_out;

    const int H = 256, W = 256;
    const int planes = in_sizes[0] / (H * W);   // N*C = 1024
    const int tilesH = H / TILE_H;              // 4

    dim3 block(LANES, TY);                      // 256 threads, x-major: wave per ty
    dim3 grid(planes * tilesH);                 // 4096 blocks
    blur2_kernel<<<grid, block, 0, stream>>>(x, kern, out, H, W, tilesH);
}